// Round 4
// baseline (128.847 us; speedup 1.0000x reference)
//
#include <hip/hip_runtime.h>
#include <math.h>

constexpr int Bn = 8, Nn = 4096, Cn = 1024, Hn = 256, Kn = 3;
constexpr float EPS = 1e-5f;
constexpr int ROWS = 32;                 // rows per colsum block
constexpr int NBLK = Nn / ROWS;          // 128 partial blocks per batch
constexpr int STRIP = 8;                 // rows per conv wave

// ---------------- kernel 1: partial column sums over N (no atomics) ----------
__global__ __launch_bounds__(256) void k_colsum(const float* __restrict__ x,
                                                float* __restrict__ partial) {
    int blk = blockIdx.x;                 // Bn * NBLK = 1024 blocks
    int b  = blk / NBLK;
    int n0 = (blk % NBLK) * ROWS;
    int c  = threadIdx.x * 4;
    const float* p = x + ((size_t)b * Nn + n0) * Cn + c;
    float4 acc = make_float4(0.f, 0.f, 0.f, 0.f);
    #pragma unroll 8
    for (int r = 0; r < ROWS; ++r) {
        float4 v = *reinterpret_cast<const float4*>(p + (size_t)r * Cn);
        acc.x += v.x; acc.y += v.y; acc.z += v.z; acc.w += v.w;
    }
    *reinterpret_cast<float4*>(partial + (size_t)blk * Cn + c) = acc;
}

// ---- kernel 2 (fused MLP): ctx reduce -> h = gelu(ctx@W1+b1) -> kern slice --
// 96 blocks = 8 batches x 12 slices of 256 outputs. Each block redundantly
// computes the full h (W1 is 1 MB, L2-resident across blocks).
__global__ __launch_bounds__(256) void k_mlp(const float* __restrict__ partial,
                                             const float* __restrict__ W1,
                                             const float* __restrict__ b1,
                                             const float* __restrict__ W2,
                                             const float* __restrict__ b2,
                                             float* __restrict__ kern) {
    int blk = blockIdx.x;
    int b = blk / 12, sl = blk % 12;
    int t = threadIdx.x;

    __shared__ float ctx[Cn];
    __shared__ float hs[Hn];

    // phase A: reduce NBLK partials -> ctx (mean)
    const float invN = 1.0f / (float)Nn;
    const float* pp = partial + (size_t)b * NBLK * Cn;
    float a0 = 0.f, a1 = 0.f, a2 = 0.f, a3 = 0.f;
    for (int p = 0; p < NBLK; ++p) {
        const float* row = pp + (size_t)p * Cn;
        a0 += row[t];
        a1 += row[t + 256];
        a2 += row[t + 512];
        a3 += row[t + 768];
    }
    ctx[t]       = a0 * invN;
    ctx[t + 256] = a1 * invN;
    ctx[t + 512] = a2 * invN;
    ctx[t + 768] = a3 * invN;
    __syncthreads();

    // phase B: full h (one column of W1 per thread), exact erf GELU
    float acc = b1[t];
    #pragma unroll 8
    for (int c = 0; c < Cn; ++c)
        acc = fmaf(ctx[c], W1[(size_t)c * Hn + t], acc);
    hs[t] = 0.5f * acc * (1.0f + erff(acc * 0.70710678118654752440f));
    __syncthreads();

    // phase C: this block's 256 outputs of h @ W2 + b2
    int m = sl * 256 + t;
    float c0 = b2[m], c1 = 0.f, c2 = 0.f, c3 = 0.f;
    const float* w2 = W2 + m;
    #pragma unroll 4
    for (int j = 0; j < Hn; j += 4) {
        c0 = fmaf(hs[j],     w2[(size_t)j       * (Cn * Kn)], c0);
        c1 = fmaf(hs[j + 1], w2[(size_t)(j + 1) * (Cn * Kn)], c1);
        c2 = fmaf(hs[j + 2], w2[(size_t)(j + 2) * (Cn * Kn)], c2);
        c3 = fmaf(hs[j + 3], w2[(size_t)(j + 3) * (Cn * Kn)], c3);
    }
    float val = (c0 + c1) + (c2 + c3);
    int c = m / Kn, k = m - c * Kn;
    kern[((size_t)b * Kn + k) * Cn + c] = val;   // transposed [B][K][C]
}

// ---- kernel 3: conv + residual + LN; one wave slides over a strip of 8 rows -
// Register sliding window: hold x[n-1], x[n]; load only x[n+1] per row.
// Read amplification 3.0x -> 1.25x. Coefficients/gamma/beta held in registers.
__global__ __launch_bounds__(256) void k_conv_ln(const float* __restrict__ x,
                                                 const float* __restrict__ kern,
                                                 const float* __restrict__ gamma,
                                                 const float* __restrict__ beta,
                                                 float* __restrict__ out) {
    int bid = blockIdx.x;                          // 1024 blocks (divisible by 8)
    int nb8 = gridDim.x >> 3;
    int sb  = (bid & 7) * nb8 + (bid >> 3);        // bijective XCD chunk swizzle
    int strip = sb * 4 + (threadIdx.x >> 6);       // 4096 strips total
    int b  = strip >> 9;                           // 512 strips per batch
    int n0 = (strip & 511) * STRIP;
    int lane = threadIdx.x & 63;

    const float4* xb = reinterpret_cast<const float4*>(x + (size_t)b * Nn * Cn);
    float4*       ob = reinterpret_cast<float4*>(out + (size_t)b * Nn * Cn);
    const float4* kb = reinterpret_cast<const float4*>(kern + (size_t)b * Kn * Cn);
    const float4* g4  = reinterpret_cast<const float4*>(gamma);
    const float4* be4 = reinterpret_cast<const float4*>(beta);
    const float4 z4 = make_float4(0.f, 0.f, 0.f, 0.f);

    float4 k0[4], k1[4], k2[4], g[4], be[4];
    float4 xm[4], xc[4], xp[4];
    #pragma unroll
    for (int k = 0; k < 4; ++k) {
        int ci = lane + (k << 6);                  // float4 index within row
        k0[k] = kb[ci];
        k1[k] = kb[ci + 256];
        k2[k] = kb[ci + 512];
        g[k]  = g4[ci];
        be[k] = be4[ci];
        xm[k] = (n0 > 0) ? xb[(size_t)(n0 - 1) * 256 + ci] : z4;
        xc[k] = xb[(size_t)n0 * 256 + ci];
    }

    #pragma unroll
    for (int i = 0; i < STRIP; ++i) {
        int n = n0 + i;
        bool hasP = (n < Nn - 1);
        #pragma unroll
        for (int k = 0; k < 4; ++k) {
            int ci = lane + (k << 6);
            xp[k] = hasP ? xb[(size_t)(n + 1) * 256 + ci] : z4;
        }

        float4 y[4];
        float s = 0.f, s2 = 0.f;
        #pragma unroll
        for (int k = 0; k < 4; ++k) {
            float4 v;
            v.x = fmaf(k0[k].x, xm[k].x, fmaf(k1[k].x, xc[k].x, fmaf(k2[k].x, xp[k].x, xc[k].x)));
            v.y = fmaf(k0[k].y, xm[k].y, fmaf(k1[k].y, xc[k].y, fmaf(k2[k].y, xp[k].y, xc[k].y)));
            v.z = fmaf(k0[k].z, xm[k].z, fmaf(k1[k].z, xc[k].z, fmaf(k2[k].z, xp[k].z, xc[k].z)));
            v.w = fmaf(k0[k].w, xm[k].w, fmaf(k1[k].w, xc[k].w, fmaf(k2[k].w, xp[k].w, xc[k].w)));
            y[k] = v;
            s  += (v.x + v.y) + (v.z + v.w);
            s2 += fmaf(v.x, v.x, fmaf(v.y, v.y, fmaf(v.z, v.z, v.w * v.w)));
        }

        #pragma unroll
        for (int off = 1; off < 64; off <<= 1) {
            s  += __shfl_xor(s,  off, 64);
            s2 += __shfl_xor(s2, off, 64);
        }

        float mu   = s * (1.0f / (float)Cn);
        float var  = fmaf(-mu, mu, s2 * (1.0f / (float)Cn));
        float rstd = rsqrtf(var + EPS);

        #pragma unroll
        for (int k = 0; k < 4; ++k) {
            int ci = lane + (k << 6);
            float4 v = y[k], o;
            o.x = fmaf((v.x - mu) * rstd, g[k].x, be[k].x);
            o.y = fmaf((v.y - mu) * rstd, g[k].y, be[k].y);
            o.z = fmaf((v.z - mu) * rstd, g[k].z, be[k].z);
            o.w = fmaf((v.w - mu) * rstd, g[k].w, be[k].w);
            ob[(size_t)n * 256 + ci] = o;
        }

        #pragma unroll
        for (int k = 0; k < 4; ++k) { xm[k] = xc[k]; xc[k] = xp[k]; }
    }
}

extern "C" void kernel_launch(void* const* d_in, const int* in_sizes, int n_in,
                              void* d_out, int out_size, void* d_ws, size_t ws_size,
                              hipStream_t stream) {
    const float* x     = (const float*)d_in[0];
    const float* W1    = (const float*)d_in[1];
    const float* b1    = (const float*)d_in[2];
    const float* W2    = (const float*)d_in[3];
    const float* b2    = (const float*)d_in[4];
    const float* gamma = (const float*)d_in[5];
    const float* beta  = (const float*)d_in[6];
    float* out = (float*)d_out;

    float* ws      = (float*)d_ws;
    float* partial = ws;                                  // 1024*1024 floats (4 MB)
    float* kern    = partial + (size_t)Bn * NBLK * Cn;    // 24576 floats

    k_colsum<<<Bn * NBLK, 256, 0, stream>>>(x, partial);
    k_mlp<<<Bn * 12, 256, 0, stream>>>(partial, W1, b1, W2, b2, kern);
    k_conv_ln<<<Bn * Nn / (4 * STRIP), 256, 0, stream>>>(x, kern, gamma, beta, out);
}

// Round 5
// 84.085 us; speedup vs baseline: 1.5323x; 1.5323x over previous
//
#include <hip/hip_runtime.h>
#include <math.h>

constexpr int Bn = 8, Nn = 4096, Cn = 1024, Hn = 256, Kn = 3;
constexpr float EPS = 1e-5f;
constexpr int ROWS = 64;                 // rows per colsum block
constexpr int NBLK = Nn / ROWS;          // 64 partial blocks per batch
constexpr int STRIP = 8;                 // rows per conv wave

// ---------------- kernel 1: partial column sums over N (no atomics) ----------
__global__ __launch_bounds__(256) void k_colsum(const float* __restrict__ x,
                                                float* __restrict__ partial) {
    int blk = blockIdx.x;                 // Bn * NBLK = 512 blocks
    int b  = blk / NBLK;
    int n0 = (blk % NBLK) * ROWS;
    int c  = threadIdx.x * 4;
    const float* p = x + ((size_t)b * Nn + n0) * Cn + c;
    float4 acc = make_float4(0.f, 0.f, 0.f, 0.f);
    #pragma unroll 8
    for (int r = 0; r < ROWS; ++r) {
        float4 v = *reinterpret_cast<const float4*>(p + (size_t)r * Cn);
        acc.x += v.x; acc.y += v.y; acc.z += v.z; acc.w += v.w;
    }
    *reinterpret_cast<float4*>(partial + (size_t)blk * Cn + c) = acc;
}

// ---- kernel 2: ctx reduce (float4) + h = gelu(ctx@W1+b1), 16-way split-K ----
// 128 blocks = 8 batches x 16 j-groups of 16. Short chains everywhere:
// phase A = 64 independent float4 loads; phase B = 64-load split-K chain.
__global__ __launch_bounds__(256) void k_mlp1(const float* __restrict__ partial,
                                              const float* __restrict__ W1,
                                              const float* __restrict__ b1,
                                              float* __restrict__ h) {
    int b  = blockIdx.x >> 4;            // 8
    int jg = blockIdx.x & 15;            // 16 j-groups
    int t  = threadIdx.x;

    __shared__ float ctx[Cn];
    __shared__ float red[16][17];        // +1 pad

    // phase A: reduce NBLK partial rows; thread owns float4 channel group t
    const float invN = 1.0f / (float)Nn;
    const float4* pp = reinterpret_cast<const float4*>(partial + (size_t)b * NBLK * Cn);
    float4 a = make_float4(0.f, 0.f, 0.f, 0.f);
    #pragma unroll 8
    for (int p = 0; p < NBLK; ++p) {
        float4 v = pp[(size_t)p * 256 + t];
        a.x += v.x; a.y += v.y; a.z += v.z; a.w += v.w;
    }
    a.x *= invN; a.y *= invN; a.z *= invN; a.w *= invN;
    reinterpret_cast<float4*>(ctx)[t] = a;
    __syncthreads();

    // phase B: 16 c-slices x 16 j; each thread sums 64 c's
    int cs = t >> 4, jl = t & 15;
    int j  = jg * 16 + jl;
    const float* w1 = W1 + j;
    int c0 = cs * 64;
    float acc = 0.f;
    #pragma unroll 8
    for (int cc = 0; cc < 64; ++cc)
        acc = fmaf(ctx[c0 + cc], w1[(size_t)(c0 + cc) * Hn], acc);
    red[cs][jl] = acc;
    __syncthreads();

    if (t < 16) {
        float v = b1[jg * 16 + t];
        #pragma unroll
        for (int i = 0; i < 16; ++i) v += red[i][t];
        h[b * Hn + jg * 16 + t] = 0.5f * v * (1.0f + erff(v * 0.70710678118654752440f));
    }
}

// ---- kernel 3: kern = h @ W2 + b2 (transposed [B][K][C]), 2-way split-H ----
// 96 blocks x 512 threads; thread chain = 128 coalesced loads.
__global__ __launch_bounds__(512) void k_mlp2(const float* __restrict__ h,
                                              const float* __restrict__ W2,
                                              const float* __restrict__ b2,
                                              float* __restrict__ kern) {
    int b  = blockIdx.y;                  // 8
    int mg = blockIdx.x;                  // 12 groups of 256 outputs
    int t  = threadIdx.x;

    __shared__ float hs[Hn];
    __shared__ float red[512];

    if (t < Hn) hs[t] = h[b * Hn + t];
    __syncthreads();

    int hh = t >> 8, ml = t & 255;
    int m  = mg * 256 + ml;
    const float* w2 = W2 + (size_t)hh * 128 * (Cn * Kn) + m;
    const float* hp = hs + hh * 128;
    float a0 = 0.f, a1 = 0.f;
    #pragma unroll 8
    for (int j = 0; j < 128; j += 2) {
        a0 = fmaf(hp[j],     w2[(size_t)j       * (Cn * Kn)], a0);
        a1 = fmaf(hp[j + 1], w2[(size_t)(j + 1) * (Cn * Kn)], a1);
    }
    red[t] = a0 + a1;
    __syncthreads();

    if (t < 256) {
        int mm = mg * 256 + t;
        float val = red[t] + red[t + 256] + b2[mm];
        int c = mm / Kn, k = mm - c * Kn;
        kern[((size_t)b * Kn + k) * Cn + c] = val;
    }
}

// ---- kernel 4: conv + residual + LN; one wave slides over a strip of 8 rows -
__global__ __launch_bounds__(256) void k_conv_ln(const float* __restrict__ x,
                                                 const float* __restrict__ kern,
                                                 const float* __restrict__ gamma,
                                                 const float* __restrict__ beta,
                                                 float* __restrict__ out) {
    int bid = blockIdx.x;                          // 1024 blocks (divisible by 8)
    int nb8 = gridDim.x >> 3;
    int sb  = (bid & 7) * nb8 + (bid >> 3);        // bijective XCD chunk swizzle
    int strip = sb * 4 + (threadIdx.x >> 6);       // 4096 strips total
    int b  = strip >> 9;                           // 512 strips per batch
    int n0 = (strip & 511) * STRIP;
    int lane = threadIdx.x & 63;

    const float4* xb = reinterpret_cast<const float4*>(x + (size_t)b * Nn * Cn);
    float4*       ob = reinterpret_cast<float4*>(out + (size_t)b * Nn * Cn);
    const float4* kb = reinterpret_cast<const float4*>(kern + (size_t)b * Kn * Cn);
    const float4* g4  = reinterpret_cast<const float4*>(gamma);
    const float4* be4 = reinterpret_cast<const float4*>(beta);
    const float4 z4 = make_float4(0.f, 0.f, 0.f, 0.f);

    float4 k0[4], k1[4], k2[4], g[4], be[4];
    float4 xm[4], xc[4], xp[4];
    #pragma unroll
    for (int k = 0; k < 4; ++k) {
        int ci = lane + (k << 6);                  // float4 index within row
        k0[k] = kb[ci];
        k1[k] = kb[ci + 256];
        k2[k] = kb[ci + 512];
        g[k]  = g4[ci];
        be[k] = be4[ci];
        xm[k] = (n0 > 0) ? xb[(size_t)(n0 - 1) * 256 + ci] : z4;
        xc[k] = xb[(size_t)n0 * 256 + ci];
    }

    #pragma unroll
    for (int i = 0; i < STRIP; ++i) {
        int n = n0 + i;
        bool hasP = (n < Nn - 1);
        #pragma unroll
        for (int k = 0; k < 4; ++k) {
            int ci = lane + (k << 6);
            xp[k] = hasP ? xb[(size_t)(n + 1) * 256 + ci] : z4;
        }

        float4 y[4];
        float s = 0.f, s2 = 0.f;
        #pragma unroll
        for (int k = 0; k < 4; ++k) {
            float4 v;
            v.x = fmaf(k0[k].x, xm[k].x, fmaf(k1[k].x, xc[k].x, fmaf(k2[k].x, xp[k].x, xc[k].x)));
            v.y = fmaf(k0[k].y, xm[k].y, fmaf(k1[k].y, xc[k].y, fmaf(k2[k].y, xp[k].y, xc[k].y)));
            v.z = fmaf(k0[k].z, xm[k].z, fmaf(k1[k].z, xc[k].z, fmaf(k2[k].z, xp[k].z, xc[k].z)));
            v.w = fmaf(k0[k].w, xm[k].w, fmaf(k1[k].w, xc[k].w, fmaf(k2[k].w, xp[k].w, xc[k].w)));
            y[k] = v;
            s  += (v.x + v.y) + (v.z + v.w);
            s2 += fmaf(v.x, v.x, fmaf(v.y, v.y, fmaf(v.z, v.z, v.w * v.w)));
        }

        #pragma unroll
        for (int off = 1; off < 64; off <<= 1) {
            s  += __shfl_xor(s,  off, 64);
            s2 += __shfl_xor(s2, off, 64);
        }

        float mu   = s * (1.0f / (float)Cn);
        float var  = fmaf(-mu, mu, s2 * (1.0f / (float)Cn));
        float rstd = rsqrtf(var + EPS);

        #pragma unroll
        for (int k = 0; k < 4; ++k) {
            int ci = lane + (k << 6);
            float4 v = y[k], o;
            o.x = fmaf((v.x - mu) * rstd, g[k].x, be[k].x);
            o.y = fmaf((v.y - mu) * rstd, g[k].y, be[k].y);
            o.z = fmaf((v.z - mu) * rstd, g[k].z, be[k].z);
            o.w = fmaf((v.w - mu) * rstd, g[k].w, be[k].w);
            ob[(size_t)n * 256 + ci] = o;
        }

        #pragma unroll
        for (int k = 0; k < 4; ++k) { xm[k] = xc[k]; xc[k] = xp[k]; }
    }
}

extern "C" void kernel_launch(void* const* d_in, const int* in_sizes, int n_in,
                              void* d_out, int out_size, void* d_ws, size_t ws_size,
                              hipStream_t stream) {
    const float* x     = (const float*)d_in[0];
    const float* W1    = (const float*)d_in[1];
    const float* b1    = (const float*)d_in[2];
    const float* W2    = (const float*)d_in[3];
    const float* b2    = (const float*)d_in[4];
    const float* gamma = (const float*)d_in[5];
    const float* beta  = (const float*)d_in[6];
    float* out = (float*)d_out;

    float* ws      = (float*)d_ws;
    float* partial = ws;                                  // 512*1024 floats (2 MB)
    float* h       = partial + (size_t)Bn * NBLK * Cn;    // 2048 floats
    float* kern    = h + Bn * Hn;                         // 24576 floats

    k_colsum<<<Bn * NBLK, 256, 0, stream>>>(x, partial);
    k_mlp1<<<Bn * 16, 256, 0, stream>>>(partial, W1, b1, h);
    dim3 g2(Cn * Kn / 256, Bn);
    k_mlp2<<<g2, 512, 0, stream>>>(h, W2, b2, kern);
    k_conv_ln<<<Bn * Nn / (4 * STRIP), 256, 0, stream>>>(x, kern, gamma, beta, out);
}

// Round 7
// 82.243 us; speedup vs baseline: 1.5667x; 1.0224x over previous
//
#include <hip/hip_runtime.h>
#include <math.h>

constexpr int Bn = 8, Nn = 4096, Cn = 1024, Hn = 256, Kn = 3;
constexpr float EPS = 1e-5f;
constexpr int ROWS = 64;                 // rows per colsum block
constexpr int NBLK = Nn / ROWS;          // 64 partial blocks per batch
constexpr int STRIP = 8;                 // rows per conv wave

typedef float v4f __attribute__((ext_vector_type(4)));

// ---------------- kernel 1: partial column sums over N (no atomics) ----------
__global__ __launch_bounds__(256) void k_colsum(const float* __restrict__ x,
                                                float* __restrict__ partial) {
    int blk = blockIdx.x;                 // Bn * NBLK = 512 blocks
    int b  = blk / NBLK;
    int n0 = (blk % NBLK) * ROWS;
    int c  = threadIdx.x * 4;
    const float* p = x + ((size_t)b * Nn + n0) * Cn + c;
    float4 acc = make_float4(0.f, 0.f, 0.f, 0.f);
    #pragma unroll 8
    for (int r = 0; r < ROWS; ++r) {
        float4 v = *reinterpret_cast<const float4*>(p + (size_t)r * Cn);
        acc.x += v.x; acc.y += v.y; acc.z += v.z; acc.w += v.w;
    }
    *reinterpret_cast<float4*>(partial + (size_t)blk * Cn + c) = acc;
}

// ---- kernel 2: ctx reduce (float4) + h = gelu(ctx@W1+b1), 16-way split-K ----
__global__ __launch_bounds__(256) void k_mlp1(const float* __restrict__ partial,
                                              const float* __restrict__ W1,
                                              const float* __restrict__ b1,
                                              float* __restrict__ h) {
    int b  = blockIdx.x >> 4;            // 8
    int jg = blockIdx.x & 15;            // 16 j-groups
    int t  = threadIdx.x;

    __shared__ float ctx[Cn];
    __shared__ float red[16][17];        // +1 pad

    const float invN = 1.0f / (float)Nn;
    const float4* pp = reinterpret_cast<const float4*>(partial + (size_t)b * NBLK * Cn);
    float4 a = make_float4(0.f, 0.f, 0.f, 0.f);
    #pragma unroll 8
    for (int p = 0; p < NBLK; ++p) {
        float4 v = pp[(size_t)p * 256 + t];
        a.x += v.x; a.y += v.y; a.z += v.z; a.w += v.w;
    }
    a.x *= invN; a.y *= invN; a.z *= invN; a.w *= invN;
    reinterpret_cast<float4*>(ctx)[t] = a;
    __syncthreads();

    int cs = t >> 4, jl = t & 15;
    int j  = jg * 16 + jl;
    const float* w1 = W1 + j;
    int c0 = cs * 64;
    float acc = 0.f;
    #pragma unroll 8
    for (int cc = 0; cc < 64; ++cc)
        acc = fmaf(ctx[c0 + cc], w1[(size_t)(c0 + cc) * Hn], acc);
    red[cs][jl] = acc;
    __syncthreads();

    if (t < 16) {
        float v = b1[jg * 16 + t];
        #pragma unroll
        for (int i = 0; i < 16; ++i) v += red[i][t];
        h[b * Hn + jg * 16 + t] = 0.5f * v * (1.0f + erff(v * 0.70710678118654752440f));
    }
}

// ---- kernel 3: kern = h @ W2 + b2 (transposed [B][K][C]), 2-way split-H ----
__global__ __launch_bounds__(512) void k_mlp2(const float* __restrict__ h,
                                              const float* __restrict__ W2,
                                              const float* __restrict__ b2,
                                              float* __restrict__ kern) {
    int b  = blockIdx.y;                  // 8
    int mg = blockIdx.x;                  // 12 groups of 256 outputs
    int t  = threadIdx.x;

    __shared__ float hs[Hn];
    __shared__ float red[512];

    if (t < Hn) hs[t] = h[b * Hn + t];
    __syncthreads();

    int hh = t >> 8, ml = t & 255;
    int m  = mg * 256 + ml;
    const float* w2 = W2 + (size_t)hh * 128 * (Cn * Kn) + m;
    const float* hp = hs + hh * 128;
    float a0 = 0.f, a1 = 0.f;
    #pragma unroll 8
    for (int j = 0; j < 128; j += 2) {
        a0 = fmaf(hp[j],     w2[(size_t)j       * (Cn * Kn)], a0);
        a1 = fmaf(hp[j + 1], w2[(size_t)(j + 1) * (Cn * Kn)], a1);
    }
    red[t] = a0 + a1;
    __syncthreads();

    if (t < 256) {
        int mm = mg * 256 + t;
        float val = red[t] + red[t + 256] + b2[mm];
        int c = mm / Kn, k = mm - c * Kn;
        kern[((size_t)b * Kn + k) * Cn + c] = val;
    }
}

// ---- kernel 4: conv + residual + LN; sliding window strip; NT stores -------
// Non-temporal out-stores keep x resident in the 256MB L3 (x=134MB fits):
// conv reads hit L3, and x stays warm for the next replay's colsum.
__global__ __launch_bounds__(256) void k_conv_ln(const float* __restrict__ x,
                                                 const float* __restrict__ kern,
                                                 const float* __restrict__ gamma,
                                                 const float* __restrict__ beta,
                                                 float* __restrict__ out) {
    int bid = blockIdx.x;                          // 1024 blocks (divisible by 8)
    int nb8 = gridDim.x >> 3;
    int sb  = (bid & 7) * nb8 + (bid >> 3);        // bijective XCD chunk swizzle
    int strip = sb * 4 + (threadIdx.x >> 6);       // 4096 strips total
    int b  = strip >> 9;                           // 512 strips per batch
    int n0 = (strip & 511) * STRIP;
    int lane = threadIdx.x & 63;

    const float4* xb = reinterpret_cast<const float4*>(x + (size_t)b * Nn * Cn);
    v4f*          ob = reinterpret_cast<v4f*>(out + (size_t)b * Nn * Cn);
    const float4* kb = reinterpret_cast<const float4*>(kern + (size_t)b * Kn * Cn);
    const float4* g4  = reinterpret_cast<const float4*>(gamma);
    const float4* be4 = reinterpret_cast<const float4*>(beta);
    const float4 z4 = make_float4(0.f, 0.f, 0.f, 0.f);

    float4 k0[4], k1[4], k2[4], g[4], be[4];
    float4 xm[4], xc[4], xp[4];
    #pragma unroll
    for (int k = 0; k < 4; ++k) {
        int ci = lane + (k << 6);                  // float4 index within row
        k0[k] = kb[ci];
        k1[k] = kb[ci + 256];
        k2[k] = kb[ci + 512];
        g[k]  = g4[ci];
        be[k] = be4[ci];
        xm[k] = (n0 > 0) ? xb[(size_t)(n0 - 1) * 256 + ci] : z4;
        xc[k] = xb[(size_t)n0 * 256 + ci];
    }

    #pragma unroll
    for (int i = 0; i < STRIP; ++i) {
        int n = n0 + i;
        bool hasP = (n < Nn - 1);
        #pragma unroll
        for (int k = 0; k < 4; ++k) {
            int ci = lane + (k << 6);
            xp[k] = hasP ? xb[(size_t)(n + 1) * 256 + ci] : z4;
        }

        float4 y[4];
        float s = 0.f, s2 = 0.f;
        #pragma unroll
        for (int k = 0; k < 4; ++k) {
            float4 v;
            v.x = fmaf(k0[k].x, xm[k].x, fmaf(k1[k].x, xc[k].x, fmaf(k2[k].x, xp[k].x, xc[k].x)));
            v.y = fmaf(k0[k].y, xm[k].y, fmaf(k1[k].y, xc[k].y, fmaf(k2[k].y, xp[k].y, xc[k].y)));
            v.z = fmaf(k0[k].z, xm[k].z, fmaf(k1[k].z, xc[k].z, fmaf(k2[k].z, xp[k].z, xc[k].z)));
            v.w = fmaf(k0[k].w, xm[k].w, fmaf(k1[k].w, xc[k].w, fmaf(k2[k].w, xp[k].w, xc[k].w)));
            y[k] = v;
            s  += (v.x + v.y) + (v.z + v.w);
            s2 += fmaf(v.x, v.x, fmaf(v.y, v.y, fmaf(v.z, v.z, v.w * v.w)));
        }

        #pragma unroll
        for (int off = 1; off < 64; off <<= 1) {
            s  += __shfl_xor(s,  off, 64);
            s2 += __shfl_xor(s2, off, 64);
        }

        float mu   = s * (1.0f / (float)Cn);
        float var  = fmaf(-mu, mu, s2 * (1.0f / (float)Cn));
        float rstd = rsqrtf(var + EPS);

        #pragma unroll
        for (int k = 0; k < 4; ++k) {
            int ci = lane + (k << 6);
            float4 v = y[k];
            v4f o;
            o.x = fmaf((v.x - mu) * rstd, g[k].x, be[k].x);
            o.y = fmaf((v.y - mu) * rstd, g[k].y, be[k].y);
            o.z = fmaf((v.z - mu) * rstd, g[k].z, be[k].z);
            o.w = fmaf((v.w - mu) * rstd, g[k].w, be[k].w);
            __builtin_nontemporal_store(o, &ob[(size_t)n * 256 + ci]);
        }

        #pragma unroll
        for (int k = 0; k < 4; ++k) { xm[k] = xc[k]; xc[k] = xp[k]; }
    }
}

extern "C" void kernel_launch(void* const* d_in, const int* in_sizes, int n_in,
                              void* d_out, int out_size, void* d_ws, size_t ws_size,
                              hipStream_t stream) {
    const float* x     = (const float*)d_in[0];
    const float* W1    = (const float*)d_in[1];
    const float* b1    = (const float*)d_in[2];
    const float* W2    = (const float*)d_in[3];
    const float* b2    = (const float*)d_in[4];
    const float* gamma = (const float*)d_in[5];
    const float* beta  = (const float*)d_in[6];
    float* out = (float*)d_out;

    float* ws      = (float*)d_ws;
    float* partial = ws;                                  // 512*1024 floats (2 MB)
    float* h       = partial + (size_t)Bn * NBLK * Cn;    // 2048 floats
    float* kern    = h + Bn * Hn;                         // 24576 floats

    k_colsum<<<Bn * NBLK, 256, 0, stream>>>(x, partial);
    k_mlp1<<<Bn * 16, 256, 0, stream>>>(partial, W1, b1, h);
    dim3 g2(Cn * Kn / 256, Bn);
    k_mlp2<<<g2, 512, 0, stream>>>(h, W2, b2, kern);
    k_conv_ln<<<Bn * Nn / (4 * STRIP), 256, 0, stream>>>(x, kern, gamma, beta, out);
}